// Round 18
// baseline (37.614 us; speedup 1.0000x reference)
//
#include <hip/hip_runtime.h>
#include <hip/hip_bf16.h>

#define NN 7
#define HH 16
#define RR 64
#define CC 8
#define NBINS (NN * RR * NN)   // 3136

#define HIST_BLOCK 1024
#define HIST_GRID  512                      // 2 blocks/CU -> 32 waves/CU (needs <=64 VGPR)
#define NTH (HIST_GRID * HIST_BLOCK)        // 524288 threads
#define NWAVES (NTH / 64)                   // 8192 waves
#define NSLOT 4                             // 12 loads in flight -> 48 data VGPRs
#define CHUNK (NSLOT * 64)                  // 256 int4 per wave chunk

typedef int v4i __attribute__((ext_vector_type(4)));

// SGPR-base + 32-bit voffset load (saves per-lane 64-bit address pairs:
// all three streams share the same voffset VGPR; bases live in SGPRs).
#define GLOADS(dest, voff, base) \
    asm volatile("global_load_dwordx4 %0, %1, %2 nt" \
                 : "=v"(dest) : "v"(voff), "s"(base))

// ---------------------------------------------------------------------------
// Kernel 1: histogram edges into (dst, rel, src) LDS bins.
// TLP probe: 32 waves/CU (2 blocks/CU) with a 64-VGPR-fitting depth-4
// barrage. Same in-flight bytes/CU as R17 (32w x 12 = 16w x 24) but double
// the independent wave contexts feeding the memory controller.
// ---------------------------------------------------------------------------
__global__ __launch_bounds__(HIST_BLOCK, 8) void rgcn_hist(
    const int* __restrict__ src, const int* __restrict__ dst,
    const int* __restrict__ et, int E, int* __restrict__ part) {
    __shared__ int bins[NBINS];
    for (int i = threadIdx.x; i < NBINS; i += HIST_BLOCK) bins[i] = 0;
    __syncthreads();

    const int tid = blockIdx.x * HIST_BLOCK + threadIdx.x;
    const int wid = tid >> 6;
    const int lane = tid & 63;
    const int E4 = E >> 2;

    for (int wbase = wid * CHUNK; wbase < E4; wbase += NWAVES * CHUNK) {
        v4i S[NSLOT], D[NSLOT], T[NSLOT];
        int voff[NSLOT];
#pragma unroll
        for (int k = 0; k < NSLOT; ++k) {
            int idx = wbase + k * 64 + lane;
            voff[k] = (idx < E4 ? idx : (E4 - 1)) << 4;  // byte offset, clamped
        }
        // issue all 12 loads back-to-back (3 streams share voff VGPRs)
#pragma unroll
        for (int k = 0; k < NSLOT; ++k) {
            GLOADS(S[k], voff[k], src);
            GLOADS(D[k], voff[k], dst);
            GLOADS(T[k], voff[k], et);
        }
        // slots 0-1 ready; 6 loads still in flight
        asm volatile("s_waitcnt vmcnt(6)" ::: "memory");
        __builtin_amdgcn_sched_barrier(0);
#pragma unroll
        for (int k = 0; k < 2; ++k) {
            const int add = (wbase + k * 64 + lane < E4) ? 1 : 0;
            atomicAdd(&bins[D[k][0] * (RR * NN) + T[k][0] * NN + S[k][0]], add);
            atomicAdd(&bins[D[k][1] * (RR * NN) + T[k][1] * NN + S[k][1]], add);
            atomicAdd(&bins[D[k][2] * (RR * NN) + T[k][2] * NN + S[k][2]], add);
            atomicAdd(&bins[D[k][3] * (RR * NN) + T[k][3] * NN + S[k][3]], add);
        }
        asm volatile("s_waitcnt vmcnt(0)" ::: "memory");
        __builtin_amdgcn_sched_barrier(0);
#pragma unroll
        for (int k = 2; k < NSLOT; ++k) {
            const int add = (wbase + k * 64 + lane < E4) ? 1 : 0;
            atomicAdd(&bins[D[k][0] * (RR * NN) + T[k][0] * NN + S[k][0]], add);
            atomicAdd(&bins[D[k][1] * (RR * NN) + T[k][1] * NN + S[k][1]], add);
            atomicAdd(&bins[D[k][2] * (RR * NN) + T[k][2] * NN + S[k][2]], add);
            atomicAdd(&bins[D[k][3] * (RR * NN) + T[k][3] * NN + S[k][3]], add);
        }
    }
    // scalar tail (E not multiple of 4; never runs for E=8M)
    for (int e = (E4 << 2) + tid; e < E; e += NTH) {
        atomicAdd(&bins[dst[e] * (RR * NN) + et[e] * NN + src[e]], 1);
    }

    __syncthreads();
    // plain coalesced store of the whole private histogram, vectorized
    int4* slice4 = reinterpret_cast<int4*>(part + blockIdx.x * NBINS);
    const int4* bins4 = reinterpret_cast<const int4*>(bins);
    for (int i2 = threadIdx.x; i2 < NBINS / 4; i2 += HIST_BLOCK)
        slice4[i2] = bins4[i2];
}

// ---------------------------------------------------------------------------
// Kernel 1b: reduce HIST_GRID partial histograms -> gbins.
// 49 blocks x 256 threads; 4 chunks of HIST_GRID/4 partials per bin.
// ---------------------------------------------------------------------------
__global__ __launch_bounds__(256) void rgcn_reduce(
    const int* __restrict__ part, int* __restrict__ gbins) {
    __shared__ int acc[4][64];
    const int lane = threadIdx.x & 63;
    const int chunk = threadIdx.x >> 6;      // 0..3
    const int bin = blockIdx.x * 64 + lane;  // 49*64 = 3136 exactly

    int s = 0;
    const int p0 = chunk * (HIST_GRID / 4);
#pragma unroll 8
    for (int k = 0; k < HIST_GRID / 4; ++k)
        s += part[(p0 + k) * NBINS + bin];
    acc[chunk][lane] = s;
    __syncthreads();
    if (chunk == 0)
        gbins[bin] = acc[0][lane] + acc[1][lane] + acc[2][lane] + acc[3][lane];
}

// ---------------------------------------------------------------------------
// Kernel 2: finish (R10 verbatim).
// ---------------------------------------------------------------------------
__global__ __launch_bounds__(1024) void rgcn_finish(
    const int* __restrict__ gbins,
    const float* __restrict__ W1,    // [R][N][H]
    const float* __restrict__ root1, // [N][H]
    const float* __restrict__ b1,    // [H]
    const float* __restrict__ W2,    // [R][H][C]
    const float* __restrict__ root2, // [H][C]
    const float* __restrict__ b2,    // [C]
    float* __restrict__ out) {       // [N][C]
    __shared__ float cntf[NN][RR][NN];
    __shared__ float w1s[RR * NN * HH]; // 7168 floats
    __shared__ float w2s[RR * HH * CC]; // 8192 floats
    __shared__ float p1[NN][HH][4];
    __shared__ float h[NN][HH];
    __shared__ float hr[NN][RR][CC];    // hr[src][r][c]
    __shared__ float p2[NN][CC][8];
    __shared__ float o[NN][CC];

    const int t = threadIdx.x;
    const int BD = 1024;
    const float4* W1v = reinterpret_cast<const float4*>(W1);
    for (int i = t; i < RR * NN * HH / 4; i += BD)
        reinterpret_cast<float4*>(w1s)[i] = W1v[i];
    const float4* W2v = reinterpret_cast<const float4*>(W2);
    for (int i = t; i < RR * HH * CC / 4; i += BD)
        reinterpret_cast<float4*>(w2s)[i] = W2v[i];
    for (int i = t; i < NN * RR; i += BD) {
        int n = i / RR, r = i % RR;
        const int* gb = gbins + n * (RR * NN) + r * NN;
        int c[NN];
        int tot = 0;
#pragma unroll
        for (int s = 0; s < NN; ++s) { c[s] = gb[s]; tot += c[s]; }
        float inv = 1.0f / (float)(tot > 0 ? tot : 1);
#pragma unroll
        for (int s = 0; s < NN; ++s) cntf[n][r][s] = (float)c[s] * inv;
    }
    __syncthreads();

    // layer 1 partials: (n,j,q), q sums r in [16q,16q+16)
    for (int i = t; i < NN * HH * 4; i += BD) {
        int n = i >> 6;            // HH*4 = 64
        int j = (i >> 2) & (HH - 1);
        int q = i & 3;
        float acc = 0.0f;
        for (int r = q * 16; r < q * 16 + 16; ++r)
            for (int s = 0; s < NN; ++s)
                acc = fmaf(cntf[n][r][s], w1s[(r * NN + s) * HH + j], acc);
        p1[n][j][q] = acc;
    }
    __syncthreads();
    for (int i = t; i < NN * HH; i += BD) {
        int n = i / HH, j = i % HH;
        float acc = root1[n * HH + j] + b1[j] +
                    p1[n][j][0] + p1[n][j][1] + p1[n][j][2] + p1[n][j][3];
        h[n][j] = fmaxf(acc, 0.0f);
    }
    __syncthreads();

    // hr[s][r][c] = sum_j h[s][j] * W2[r][j][c]
    for (int i = t; i < NN * RR * CC; i += BD) {
        int s = i / (RR * CC);
        int rem = i % (RR * CC);
        int r = rem / CC, c = rem % CC;
        float acc = 0.0f;
        for (int j = 0; j < HH; ++j)
            acc = fmaf(h[s][j], w2s[(r * HH + j) * CC + c], acc);
        hr[s][r][c] = acc;
    }
    __syncthreads();

    // layer 2 partials: (n,c,q), q sums r in [8q,8q+8); q==0 adds root+bias
    for (int i = t; i < NN * CC * 8; i += BD) {
        int n = i >> 6;            // CC*8 = 64
        int c = (i >> 3) & (CC - 1);
        int q = i & 7;
        float acc = 0.0f;
        for (int r = q * 8; r < q * 8 + 8; ++r)
            for (int s = 0; s < NN; ++s)
                acc = fmaf(cntf[n][r][s], hr[s][r][c], acc);
        if (q == 0) {
            for (int j = 0; j < HH; ++j)
                acc = fmaf(h[n][j], root2[j * CC + c], acc);
            acc += b2[c];
        }
        p2[n][c][q] = acc;
    }
    __syncthreads();
    for (int i = t; i < NN * CC; i += BD) {
        int n = i / CC, c = i % CC;
        float acc = 0.0f;
        for (int q = 0; q < 8; ++q) acc += p2[n][c][q];
        o[n][c] = acc;
    }
    __syncthreads();

    // row-wise log_softmax, one thread per node
    if (t < NN) {
        float m = -1e30f;
        for (int c = 0; c < CC; ++c) m = fmaxf(m, o[t][c]);
        float sum = 0.0f;
        for (int c = 0; c < CC; ++c) sum += __expf(o[t][c] - m);
        float lse = m + __logf(sum);
        for (int c = 0; c < CC; ++c) out[t * CC + c] = o[t][c] - lse;
    }
}

extern "C" void kernel_launch(void* const* d_in, const int* in_sizes, int n_in,
                              void* d_out, int out_size, void* d_ws, size_t ws_size,
                              hipStream_t stream) {
    // input order: x, edge_index, edge_type, W1, root1, b1, W2, root2, b2
    const int* edge_index = (const int*)d_in[1];
    const int* edge_type  = (const int*)d_in[2];
    const float* W1    = (const float*)d_in[3];
    const float* root1 = (const float*)d_in[4];
    const float* b1    = (const float*)d_in[5];
    const float* W2    = (const float*)d_in[6];
    const float* root2 = (const float*)d_in[7];
    const float* b2    = (const float*)d_in[8];
    float* out = (float*)d_out;

    const int E = in_sizes[2];              // num edges
    const int* src = edge_index;            // edge_index[0]
    const int* dst = edge_index + E;        // edge_index[1]

    int* part  = (int*)d_ws;                       // 512 * 3136 ints = 6.4 MB
    int* gbins = part + HIST_GRID * NBINS;         // 3136 ints

    rgcn_hist<<<HIST_GRID, HIST_BLOCK, 0, stream>>>(src, dst, edge_type, E, part);
    rgcn_reduce<<<49, 256, 0, stream>>>(part, gbins);
    rgcn_finish<<<1, 1024, 0, stream>>>(gbins, W1, root1, b1, W2, root2, b2, out);
}

// Round 19
// 32.895 us; speedup vs baseline: 1.1435x; 1.1435x over previous
//
#include <hip/hip_runtime.h>
#include <hip/hip_bf16.h>

#define NN 7
#define HH 16
#define RR 64
#define CC 8
#define NBINS (NN * RR * NN)   // 3136

#define HIST_BLOCK 1024
#define HIST_GRID  256                      // 1 block/CU, 16 waves/CU, 128-VGPR cap
#define NT (HIST_GRID * HIST_BLOCK)         // 262144 threads
#define NWAVES (NT / 64)                    // 4096 waves
#define NSLOT 8
#define CHUNK (NSLOT * 64)                  // 512 int4 per wave chunk (8 KB/array)

typedef int v4i __attribute__((ext_vector_type(4)));

// nt: 96 MB single-pass stream, zero reuse -> skip L2/L3 allocation (R17: -1.7us)
#define GLOAD(dest, p) \
    asm volatile("global_load_dwordx4 %0, %1, off nt" : "=v"(dest) : "v"(p))

// ---------------------------------------------------------------------------
// Kernel 1: histogram edges into (dst, rel, src) LDS bins. R17 verbatim —
// the best-measured configuration:
//  * 16 waves/CU, 1 block/CU (R18 proved 32 waves/CU regresses: shared LDS
//    pipe + halved barrage depth + doubled flush).
//  * wave-contiguous 8-slot asm barrage, 24 loads in flight, counted vmcnt
//    (R12-R14 proved the compiler otherwise collapses pipelines to depth-1).
//  * nt cache policy (R17: skip L2/L3 alloc on the zero-reuse stream).
// Hist runs at ~3.5 TB/s — the empirical cold-read ceiling for this pattern
// on this chip (depth/convoy/page-locality/atomics/TLP all falsified,
// R10-R18).
// ---------------------------------------------------------------------------
__global__ __launch_bounds__(HIST_BLOCK) void rgcn_hist(
    const int* __restrict__ src, const int* __restrict__ dst,
    const int* __restrict__ et, int E, int* __restrict__ part) {
    __shared__ int bins[NBINS];
    for (int i = threadIdx.x; i < NBINS; i += HIST_BLOCK) bins[i] = 0;
    __syncthreads();

    const int tid = blockIdx.x * HIST_BLOCK + threadIdx.x;
    const int wid = tid >> 6;
    const int lane = tid & 63;
    const int E4 = E >> 2;
    const v4i* s4 = reinterpret_cast<const v4i*>(src);
    const v4i* d4 = reinterpret_cast<const v4i*>(dst);
    const v4i* t4 = reinterpret_cast<const v4i*>(et);

    for (int wbase = wid * CHUNK; wbase < E4; wbase += NWAVES * CHUNK) {
        v4i S[NSLOT], D[NSLOT], T[NSLOT];
        int ix[NSLOT];
#pragma unroll
        for (int k = 0; k < NSLOT; ++k) {
            int idx = wbase + k * 64 + lane;
            ix[k] = idx < E4 ? idx : (E4 - 1);   // clamp OOB
        }
        // issue all 24 loads back-to-back, program order
#pragma unroll
        for (int k = 0; k < NSLOT; ++k) {
            GLOAD(S[k], s4 + ix[k]);
            GLOAD(D[k], d4 + ix[k]);
            GLOAD(T[k], t4 + ix[k]);
        }
        // first 12 loads (slots 0-3) done; 12 still in flight
        asm volatile("s_waitcnt vmcnt(12)" ::: "memory");
        __builtin_amdgcn_sched_barrier(0);
#pragma unroll
        for (int k = 0; k < 4; ++k) {
            const int add = (wbase + k * 64 + lane < E4) ? 1 : 0;  // per-lane
            atomicAdd(&bins[D[k][0] * (RR * NN) + T[k][0] * NN + S[k][0]], add);
            atomicAdd(&bins[D[k][1] * (RR * NN) + T[k][1] * NN + S[k][1]], add);
            atomicAdd(&bins[D[k][2] * (RR * NN) + T[k][2] * NN + S[k][2]], add);
            atomicAdd(&bins[D[k][3] * (RR * NN) + T[k][3] * NN + S[k][3]], add);
        }
        asm volatile("s_waitcnt vmcnt(0)" ::: "memory");
        __builtin_amdgcn_sched_barrier(0);
#pragma unroll
        for (int k = 4; k < NSLOT; ++k) {
            const int add = (wbase + k * 64 + lane < E4) ? 1 : 0;
            atomicAdd(&bins[D[k][0] * (RR * NN) + T[k][0] * NN + S[k][0]], add);
            atomicAdd(&bins[D[k][1] * (RR * NN) + T[k][1] * NN + S[k][1]], add);
            atomicAdd(&bins[D[k][2] * (RR * NN) + T[k][2] * NN + S[k][2]], add);
            atomicAdd(&bins[D[k][3] * (RR * NN) + T[k][3] * NN + S[k][3]], add);
        }
    }
    // scalar tail (E not multiple of 4; never runs for E=8M)
    for (int e = (E4 << 2) + tid; e < E; e += NT) {
        atomicAdd(&bins[dst[e] * (RR * NN) + et[e] * NN + src[e]], 1);
    }

    __syncthreads();
    // plain coalesced store of the whole private histogram, vectorized
    int4* slice4 = reinterpret_cast<int4*>(part + blockIdx.x * NBINS);
    const int4* bins4 = reinterpret_cast<const int4*>(bins);
    for (int i2 = threadIdx.x; i2 < NBINS / 4; i2 += HIST_BLOCK)
        slice4[i2] = bins4[i2];
}

// ---------------------------------------------------------------------------
// Kernel 1b: reduce HIST_GRID partial histograms -> gbins.
// ---------------------------------------------------------------------------
__global__ __launch_bounds__(256) void rgcn_reduce(
    const int* __restrict__ part, int* __restrict__ gbins) {
    __shared__ int acc[4][64];
    const int lane = threadIdx.x & 63;
    const int chunk = threadIdx.x >> 6;      // 0..3
    const int bin = blockIdx.x * 64 + lane;  // 49*64 = 3136 exactly

    int s = 0;
    const int p0 = chunk * (HIST_GRID / 4);
#pragma unroll 8
    for (int k = 0; k < HIST_GRID / 4; ++k)
        s += part[(p0 + k) * NBINS + bin];
    acc[chunk][lane] = s;
    __syncthreads();
    if (chunk == 0)
        gbins[bin] = acc[0][lane] + acc[1][lane] + acc[2][lane] + acc[3][lane];
}

// ---------------------------------------------------------------------------
// Kernel 2: finish — all the dense math on one 1024-thread block.
// ---------------------------------------------------------------------------
__global__ __launch_bounds__(1024) void rgcn_finish(
    const int* __restrict__ gbins,
    const float* __restrict__ W1,    // [R][N][H]
    const float* __restrict__ root1, // [N][H]
    const float* __restrict__ b1,    // [H]
    const float* __restrict__ W2,    // [R][H][C]
    const float* __restrict__ root2, // [H][C]
    const float* __restrict__ b2,    // [C]
    float* __restrict__ out) {       // [N][C]
    __shared__ float cntf[NN][RR][NN];
    __shared__ float w1s[RR * NN * HH]; // 7168 floats
    __shared__ float w2s[RR * HH * CC]; // 8192 floats
    __shared__ float p1[NN][HH][4];
    __shared__ float h[NN][HH];
    __shared__ float hr[NN][RR][CC];    // hr[src][r][c]
    __shared__ float p2[NN][CC][8];
    __shared__ float o[NN][CC];

    const int t = threadIdx.x;
    const int BD = 1024;
    const float4* W1v = reinterpret_cast<const float4*>(W1);
    for (int i = t; i < RR * NN * HH / 4; i += BD)
        reinterpret_cast<float4*>(w1s)[i] = W1v[i];
    const float4* W2v = reinterpret_cast<const float4*>(W2);
    for (int i = t; i < RR * HH * CC / 4; i += BD)
        reinterpret_cast<float4*>(w2s)[i] = W2v[i];
    for (int i = t; i < NN * RR; i += BD) {
        int n = i / RR, r = i % RR;
        const int* gb = gbins + n * (RR * NN) + r * NN;
        int c[NN];
        int tot = 0;
#pragma unroll
        for (int s = 0; s < NN; ++s) { c[s] = gb[s]; tot += c[s]; }
        float inv = 1.0f / (float)(tot > 0 ? tot : 1);
#pragma unroll
        for (int s = 0; s < NN; ++s) cntf[n][r][s] = (float)c[s] * inv;
    }
    __syncthreads();

    // layer 1 partials: (n,j,q), q sums r in [16q,16q+16)
    for (int i = t; i < NN * HH * 4; i += BD) {
        int n = i >> 6;            // HH*4 = 64
        int j = (i >> 2) & (HH - 1);
        int q = i & 3;
        float acc = 0.0f;
        for (int r = q * 16; r < q * 16 + 16; ++r)
            for (int s = 0; s < NN; ++s)
                acc = fmaf(cntf[n][r][s], w1s[(r * NN + s) * HH + j], acc);
        p1[n][j][q] = acc;
    }
    __syncthreads();
    for (int i = t; i < NN * HH; i += BD) {
        int n = i / HH, j = i % HH;
        float acc = root1[n * HH + j] + b1[j] +
                    p1[n][j][0] + p1[n][j][1] + p1[n][j][2] + p1[n][j][3];
        h[n][j] = fmaxf(acc, 0.0f);
    }
    __syncthreads();

    // hr[s][r][c] = sum_j h[s][j] * W2[r][j][c]
    for (int i = t; i < NN * RR * CC; i += BD) {
        int s = i / (RR * CC);
        int rem = i % (RR * CC);
        int r = rem / CC, c = rem % CC;
        float acc = 0.0f;
        for (int j = 0; j < HH; ++j)
            acc = fmaf(h[s][j], w2s[(r * HH + j) * CC + c], acc);
        hr[s][r][c] = acc;
    }
    __syncthreads();

    // layer 2 partials: (n,c,q), q sums r in [8q,8q+8); q==0 adds root+bias
    for (int i = t; i < NN * CC * 8; i += BD) {
        int n = i >> 6;            // CC*8 = 64
        int c = (i >> 3) & (CC - 1);
        int q = i & 7;
        float acc = 0.0f;
        for (int r = q * 8; r < q * 8 + 8; ++r)
            for (int s = 0; s < NN; ++s)
                acc = fmaf(cntf[n][r][s], hr[s][r][c], acc);
        if (q == 0) {
            for (int j = 0; j < HH; ++j)
                acc = fmaf(h[n][j], root2[j * CC + c], acc);
            acc += b2[c];
        }
        p2[n][c][q] = acc;
    }
    __syncthreads();
    for (int i = t; i < NN * CC; i += BD) {
        int n = i / CC, c = i % CC;
        float acc = 0.0f;
        for (int q = 0; q < 8; ++q) acc += p2[n][c][q];
        o[n][c] = acc;
    }
    __syncthreads();

    // row-wise log_softmax, one thread per node
    if (t < NN) {
        float m = -1e30f;
        for (int c = 0; c < CC; ++c) m = fmaxf(m, o[t][c]);
        float sum = 0.0f;
        for (int c = 0; c < CC; ++c) sum += __expf(o[t][c] - m);
        float lse = m + __logf(sum);
        for (int c = 0; c < CC; ++c) out[t * CC + c] = o[t][c] - lse;
    }
}

extern "C" void kernel_launch(void* const* d_in, const int* in_sizes, int n_in,
                              void* d_out, int out_size, void* d_ws, size_t ws_size,
                              hipStream_t stream) {
    // input order: x, edge_index, edge_type, W1, root1, b1, W2, root2, b2
    const int* edge_index = (const int*)d_in[1];
    const int* edge_type  = (const int*)d_in[2];
    const float* W1    = (const float*)d_in[3];
    const float* root1 = (const float*)d_in[4];
    const float* b1    = (const float*)d_in[5];
    const float* W2    = (const float*)d_in[6];
    const float* root2 = (const float*)d_in[7];
    const float* b2    = (const float*)d_in[8];
    float* out = (float*)d_out;

    const int E = in_sizes[2];              // num edges
    const int* src = edge_index;            // edge_index[0]
    const int* dst = edge_index + E;        // edge_index[1]

    int* part  = (int*)d_ws;                       // 256 * 3136 ints = 3.2 MB
    int* gbins = part + HIST_GRID * NBINS;         // 3136 ints

    rgcn_hist<<<HIST_GRID, HIST_BLOCK, 0, stream>>>(src, dst, edge_type, E, part);
    rgcn_reduce<<<49, 256, 0, stream>>>(part, gbins);
    rgcn_finish<<<1, 1024, 0, stream>>>(gbins, W1, root1, b1, W2, root2, b2, out);
}